// Round 2
// baseline (2016.108 us; speedup 1.0000x reference)
//
#include <hip/hip_runtime.h>
#include <math.h>

#define NHEADS 12
#define HD 64
#define BB 16
#define NN 1025
#define CC 768
#define MM (BB * NN)                    // 16400
#define QSZ (BB * NHEADS * NN * HD)     // 12,595,200 floats per tensor

__device__ __forceinline__ int imin(int a, int b) { return a < b ? a : b; }

// ---------------- K1: QKV GEMM, scatter epilogue to [s][b][h][t][d] ----------------
__global__ __launch_bounds__(256) void qkv_gemm(const float* __restrict__ A,
                                                const float* __restrict__ Bw,
                                                float* __restrict__ qkv) {
    __shared__ float As[16][68];
    __shared__ float Bs[16][68];
    const int tid = threadIdx.x;
    const int tx = tid & 15, ty = tid >> 4;
    const int m0 = blockIdx.x * 64;
    const int n0 = blockIdx.y * 64;
    const int s    = n0 / CC;                 // 0:q 1:k 2:v
    const int head = (n0 - s * CC) / HD;      // 0..11

    const int ar = tid >> 2;          // 0..63
    const int ak = (tid & 3) * 4;     // 0,4,8,12
    const int br = tid >> 4;          // 0..15
    const int bc = (tid & 15) * 4;    // 0..60

    const float* Aptr = A + (size_t)imin(m0 + ar, MM - 1) * CC;
    float acc[4][4] = {};

    for (int k0 = 0; k0 < CC; k0 += 16) {
        float4 a = *(const float4*)(Aptr + k0 + ak);
        float4 b = *(const float4*)(Bw + (size_t)(k0 + br) * (3 * CC) + n0 + bc);
        As[ak + 0][ar] = a.x; As[ak + 1][ar] = a.y;
        As[ak + 2][ar] = a.z; As[ak + 3][ar] = a.w;
        *(float4*)&Bs[br][bc] = b;
        __syncthreads();
#pragma unroll
        for (int k = 0; k < 16; ++k) {
            float4 av = *(const float4*)&As[k][ty * 4];
            float4 bv = *(const float4*)&Bs[k][tx * 4];
            float aa[4] = {av.x, av.y, av.z, av.w};
            float bb[4] = {bv.x, bv.y, bv.z, bv.w};
#pragma unroll
            for (int r = 0; r < 4; ++r)
#pragma unroll
                for (int c = 0; c < 4; ++c) acc[r][c] = fmaf(aa[r], bb[c], acc[r][c]);
        }
        __syncthreads();
    }
#pragma unroll
    for (int r = 0; r < 4; ++r) {
        int m = m0 + ty * 4 + r;
        if (m < MM) {
            int b = m / NN, t = m - b * NN;
            float* dst = qkv + (size_t)s * QSZ +
                         ((size_t)((b * NHEADS + head) * NN + t)) * HD + tx * 4;
            float4 o = {acc[r][0], acc[r][1], acc[r][2], acc[r][3]};
            *(float4*)dst = o;
        }
    }
}

// ---------------- K2: RMSNorm + RoPE (one wave per row), fold 1/sqrt(d) into q ----
__global__ __launch_bounds__(256) void norm_rope(float* __restrict__ Q,
                                                 float* __restrict__ K,
                                                 const float* __restrict__ qw,
                                                 const float* __restrict__ kw) {
    const int lane = threadIdx.x & 63;
    const int widx = threadIdx.x >> 6;
    const int rid  = blockIdx.x * 4 + widx;        // 0..196799
    const bool isq = (blockIdx.y == 0);
    float* base = (isq ? Q : K) + (size_t)rid * HD;
    const float* w = isq ? qw : kw;
    const int t = rid % NN;

    float v = base[lane];
    float ss = v * v;
#pragma unroll
    for (int o = 32; o; o >>= 1) ss += __shfl_xor(ss, o);
    float r = 1.0f / sqrtf(ss * (1.0f / 64.0f) + 1e-6f);
    v = v * r * w[lane];

    float partner = __shfl_xor(v, 32);
    if (t > 0) {
        int p   = t - 1;
        int pos = (lane < 32) ? (p & 31) : (p >> 5);
        int j   = lane & 15;
        // inv_freq = 10000^(-j/16) = exp2(-j/16 * log2(10000))
        float invf = exp2f((float)j * (-13.287712379549449f / 16.0f));
        float ang  = (float)pos * invf;
        float c = cosf(ang), sn = sinf(ang);
        float rh = (lane < 32) ? -partner : partner;
        v = v * c + rh * sn;
    }
    if (isq) v *= 0.125f;   // fold d^-0.5 score scale into q
    base[lane] = v;
}

// ---------------- K3: flash attention, 64-query blocks, 64-key chunks -------------
__global__ __launch_bounds__(256) void attn(const float* __restrict__ Q,
                                            const float* __restrict__ K,
                                            const float* __restrict__ V,
                                            float* __restrict__ O) {
    __shared__ float qt[64][68];   // Q^T [d][i]
    __shared__ float kt[64][68];   // K^T [d][j]
    __shared__ float vs[64][68];   // V   [j][d]
    __shared__ float pt[64][68];   // P^T [j][i]
    const int tid = threadIdx.x;
    const int tx = tid & 15, ty = tid >> 4;
    const int bh = blockIdx.y;               // 0..191
    const int q0 = blockIdx.x * 64;
    const float* Qb = Q + (size_t)bh * NN * HD;
    const float* Kb = K + (size_t)bh * NN * HD;
    const float* Vb = V + (size_t)bh * NN * HD;

    // stage Q transposed: full 64 rows x 64 dims = 1024 float4s, 4 per thread
#pragma unroll
    for (int rep = 0; rep < 4; ++rep) {
        int idx = tid + rep * 256;
        int i = idx >> 4;              // 0..63
        int d = (idx & 15) * 4;        // 0..60
        int qrow = imin(q0 + i, NN - 1);
        float4 a = *(const float4*)(Qb + (size_t)qrow * HD + d);
        qt[d + 0][i] = a.x; qt[d + 1][i] = a.y;
        qt[d + 2][i] = a.z; qt[d + 3][i] = a.w;
    }

    float acc[4][4] = {};
    float mr[4] = {-INFINITY, -INFINITY, -INFINITY, -INFINITY};
    float lr[4] = {0.f, 0.f, 0.f, 0.f};

    for (int j0 = 0; j0 < NN; j0 += 64) {
        const int nk = imin(64, NN - j0);
        // stage K^T and V: full 64x64 tiles
#pragma unroll
        for (int rep = 0; rep < 4; ++rep) {
            int idx = tid + rep * 256;
            int j = idx >> 4;
            int d = (idx & 15) * 4;
            int krow = imin(j0 + j, NN - 1);
            float4 a = *(const float4*)(Kb + (size_t)krow * HD + d);
            kt[d + 0][j] = a.x; kt[d + 1][j] = a.y;
            kt[d + 2][j] = a.z; kt[d + 3][j] = a.w;
            float4 b = *(const float4*)(Vb + (size_t)krow * HD + d);
            *(float4*)&vs[j][d] = b;
        }
        __syncthreads();

        float sv[4][4] = {};
#pragma unroll 8
        for (int d = 0; d < 64; ++d) {
            float4 av = *(const float4*)&qt[d][ty * 4];
            float4 bv = *(const float4*)&kt[d][tx * 4];
            float aa[4] = {av.x, av.y, av.z, av.w};
            float bb[4] = {bv.x, bv.y, bv.z, bv.w};
#pragma unroll
            for (int r = 0; r < 4; ++r)
#pragma unroll
                for (int c = 0; c < 4; ++c) sv[r][c] = fmaf(aa[r], bb[c], sv[r][c]);
        }
        if (nk < 64) {
#pragma unroll
            for (int r = 0; r < 4; ++r)
#pragma unroll
                for (int c = 0; c < 4; ++c)
                    if (tx * 4 + c >= nk) sv[r][c] = -1e30f;
        }
#pragma unroll
        for (int r = 0; r < 4; ++r) {
            float rm = fmaxf(fmaxf(sv[r][0], sv[r][1]), fmaxf(sv[r][2], sv[r][3]));
#pragma unroll
            for (int o = 8; o; o >>= 1) rm = fmaxf(rm, __shfl_xor(rm, o));
            float mnew = fmaxf(mr[r], rm);
            float corr = __expf(mr[r] - mnew);
            mr[r] = mnew;
            float rs = 0.f;
#pragma unroll
            for (int c = 0; c < 4; ++c) {
                float p = __expf(sv[r][c] - mnew);
                sv[r][c] = p;
                rs += p;
            }
#pragma unroll
            for (int o = 8; o; o >>= 1) rs += __shfl_xor(rs, o);
            lr[r] = lr[r] * corr + rs;
#pragma unroll
            for (int c = 0; c < 4; ++c) {
                acc[r][c] *= corr;
                pt[tx * 4 + c][ty * 4 + r] = sv[r][c];
            }
        }
        __syncthreads();
#pragma unroll 8
        for (int j = 0; j < 64; ++j) {
            float4 av = *(const float4*)&pt[j][ty * 4];
            float4 bv = *(const float4*)&vs[j][tx * 4];
            float aa[4] = {av.x, av.y, av.z, av.w};
            float bb[4] = {bv.x, bv.y, bv.z, bv.w};
#pragma unroll
            for (int r = 0; r < 4; ++r)
#pragma unroll
                for (int c = 0; c < 4; ++c) acc[r][c] = fmaf(aa[r], bb[c], acc[r][c]);
        }
        __syncthreads();
    }

    const int b = bh / NHEADS, h = bh - b * NHEADS;
#pragma unroll
    for (int r = 0; r < 4; ++r) {
        int q = q0 + ty * 4 + r;
        if (q < NN) {
            float inv = 1.0f / lr[r];
            float4 o = {acc[r][0] * inv, acc[r][1] * inv, acc[r][2] * inv, acc[r][3] * inv};
            *(float4*)(O + ((size_t)(b * NN + q)) * CC + h * HD + tx * 4) = o;
        }
    }
}

// ---------------- K4: output projection GEMM + bias -------------------------------
__global__ __launch_bounds__(256) void proj_gemm(const float* __restrict__ A,
                                                 const float* __restrict__ Bw,
                                                 const float* __restrict__ bias,
                                                 float* __restrict__ out) {
    __shared__ float As[16][68];
    __shared__ float Bs[16][68];
    const int tid = threadIdx.x;
    const int tx = tid & 15, ty = tid >> 4;
    const int m0 = blockIdx.x * 64;
    const int n0 = blockIdx.y * 64;

    const int ar = tid >> 2;
    const int ak = (tid & 3) * 4;
    const int br = tid >> 4;
    const int bc = (tid & 15) * 4;

    const float* Aptr = A + (size_t)imin(m0 + ar, MM - 1) * CC;
    float acc[4][4] = {};

    for (int k0 = 0; k0 < CC; k0 += 16) {
        float4 a = *(const float4*)(Aptr + k0 + ak);
        float4 b = *(const float4*)(Bw + (size_t)(k0 + br) * CC + n0 + bc);
        As[ak + 0][ar] = a.x; As[ak + 1][ar] = a.y;
        As[ak + 2][ar] = a.z; As[ak + 3][ar] = a.w;
        *(float4*)&Bs[br][bc] = b;
        __syncthreads();
#pragma unroll
        for (int k = 0; k < 16; ++k) {
            float4 av = *(const float4*)&As[k][ty * 4];
            float4 bv = *(const float4*)&Bs[k][tx * 4];
            float aa[4] = {av.x, av.y, av.z, av.w};
            float bb[4] = {bv.x, bv.y, bv.z, bv.w};
#pragma unroll
            for (int r = 0; r < 4; ++r)
#pragma unroll
                for (int c = 0; c < 4; ++c) acc[r][c] = fmaf(aa[r], bb[c], acc[r][c]);
        }
        __syncthreads();
    }
#pragma unroll
    for (int r = 0; r < 4; ++r) {
        int m = m0 + ty * 4 + r;
        if (m < MM) {
            int n = n0 + tx * 4;
            float4 o = {acc[r][0] + bias[n + 0], acc[r][1] + bias[n + 1],
                        acc[r][2] + bias[n + 2], acc[r][3] + bias[n + 3]};
            *(float4*)(out + (size_t)m * CC + n) = o;
        }
    }
}

extern "C" void kernel_launch(void* const* d_in, const int* in_sizes, int n_in,
                              void* d_out, int out_size, void* d_ws, size_t ws_size,
                              hipStream_t stream) {
    const float* x      = (const float*)d_in[0];
    const float* qkv_w  = (const float*)d_in[1];
    const float* proj_w = (const float*)d_in[2];
    const float* proj_b = (const float*)d_in[3];
    const float* qnw    = (const float*)d_in[4];
    const float* knw    = (const float*)d_in[5];

    float* ws = (float*)d_ws;
    float* Q = ws;
    float* K = ws + (size_t)QSZ;
    float* V = ws + (size_t)2 * QSZ;
    float* O = ws + (size_t)3 * QSZ;

    qkv_gemm<<<dim3((MM + 63) / 64, 36), 256, 0, stream>>>(x, qkv_w, ws);
    norm_rope<<<dim3(BB * NHEADS * NN / 4, 2), 256, 0, stream>>>(Q, K, qnw, knw);
    attn<<<dim3((NN + 63) / 64, BB * NHEADS), 256, 0, stream>>>(Q, K, V, O);
    proj_gemm<<<dim3((MM + 63) / 64, CC / 64), 256, 0, stream>>>(O, proj_w, proj_b, (float*)d_out);
}

// Round 4
// 1521.502 us; speedup vs baseline: 1.3251x; 1.3251x over previous
//
#include <hip/hip_runtime.h>
#include <math.h>

#define NHEADS 12
#define HD 64
#define BB 16
#define NN 1025
#define CC 768
#define MM (BB * NN)                       // 16400
#define QSZ ((size_t)BB * NHEADS * NN * HD)   // elements per bf16 plane (q,k)
#define NNP 1032                           // padded t-stride for V^T (16B-aligned rows)
#define VTSZ ((size_t)BB * NHEADS * HD * NNP)

typedef __attribute__((ext_vector_type(8))) short short8;       // bf16x8 MFMA frag
typedef __attribute__((ext_vector_type(4))) float f32x4;        // MFMA acc
typedef __attribute__((ext_vector_type(4))) unsigned short us4; // 4x bf16 store

__device__ __forceinline__ int imin(int a, int b) { return a < b ? a : b; }

__device__ __forceinline__ unsigned short f2bf(float f) {   // RTNE fp32->bf16 bits
    unsigned u = __float_as_uint(f);
    u += 0x7FFF + ((u >> 16) & 1);
    return (unsigned short)(u >> 16);
}
__device__ __forceinline__ float bf2f(unsigned short b) {
    return __uint_as_float(((unsigned)b) << 16);
}

// ---------------- K1: QKV GEMM (VALU fp32), epilogue splits to bf16 hi/lo planes ---
// Q,K planes: [bh][t][d]; V planes transposed: [bh][d][t] (stride NNP, pads zeroed)
__global__ __launch_bounds__(256) void qkv_gemm(const float* __restrict__ A,
                                                const float* __restrict__ Bw,
                                                unsigned short* __restrict__ Qhi,
                                                unsigned short* __restrict__ Qlo,
                                                unsigned short* __restrict__ Khi,
                                                unsigned short* __restrict__ Klo,
                                                unsigned short* __restrict__ Vth,
                                                unsigned short* __restrict__ Vtl) {
    __shared__ float As[16][68];
    __shared__ float Bs[16][68];
    const int tid = threadIdx.x;
    const int tx = tid & 15, ty = tid >> 4;
    const int m0 = blockIdx.x * 64;
    const int n0 = blockIdx.y * 64;
    const int s    = n0 / CC;                 // 0:q 1:k 2:v
    const int head = (n0 - s * CC) / HD;      // 0..11

    const int ar = tid >> 2;
    const int ak = (tid & 3) * 4;
    const int br = tid >> 4;
    const int bc = (tid & 15) * 4;

    const float* Aptr = A + (size_t)imin(m0 + ar, MM - 1) * CC;
    float acc[4][4] = {};

    for (int k0 = 0; k0 < CC; k0 += 16) {
        float4 a = *(const float4*)(Aptr + k0 + ak);
        float4 b = *(const float4*)(Bw + (size_t)(k0 + br) * (3 * CC) + n0 + bc);
        As[ak + 0][ar] = a.x; As[ak + 1][ar] = a.y;
        As[ak + 2][ar] = a.z; As[ak + 3][ar] = a.w;
        *(float4*)&Bs[br][bc] = b;
        __syncthreads();
#pragma unroll
        for (int k = 0; k < 16; ++k) {
            float4 av = *(const float4*)&As[k][ty * 4];
            float4 bv = *(const float4*)&Bs[k][tx * 4];
            float aa[4] = {av.x, av.y, av.z, av.w};
            float bb[4] = {bv.x, bv.y, bv.z, bv.w};
#pragma unroll
            for (int r = 0; r < 4; ++r)
#pragma unroll
                for (int c = 0; c < 4; ++c) acc[r][c] = fmaf(aa[r], bb[c], acc[r][c]);
        }
        __syncthreads();
    }

#pragma unroll
    for (int r = 0; r < 4; ++r) {
        int m = m0 + ty * 4 + r;
        if (m >= MM) continue;
        int b = m / NN, t = m - b * NN;
        int bh = b * NHEADS + head;
        if (s < 2) {
            unsigned short* Ph = (s == 0) ? Qhi : Khi;
            unsigned short* Pl = (s == 0) ? Qlo : Klo;
            us4 h4, l4;
#pragma unroll
            for (int c = 0; c < 4; ++c) {
                float v = acc[r][c];
                unsigned short hb = f2bf(v);
                unsigned short lb = f2bf(v - bf2f(hb));
                h4[c] = hb; l4[c] = lb;
            }
            size_t idx = ((size_t)bh * NN + t) * HD + tx * 4;
            *(us4*)(Ph + idx) = h4;
            *(us4*)(Pl + idx) = l4;
        } else {
#pragma unroll
            for (int c = 0; c < 4; ++c) {
                int d = tx * 4 + c;
                float v = acc[r][c];
                unsigned short hb = f2bf(v);
                unsigned short lb = f2bf(v - bf2f(hb));
                size_t idx = ((size_t)bh * HD + d) * NNP + t;
                Vth[idx] = hb;
                Vtl[idx] = lb;
                if (t == NN - 1) {   // zero the 7 pad columns so tail reads are clean
#pragma unroll
                    for (int tt = 1; tt <= 7; ++tt) { Vth[idx + tt] = 0; Vtl[idx + tt] = 0; }
                }
            }
        }
    }
}

// ---------------- K2: RMSNorm + RoPE on bf16 hi/lo planes --------------------------
__global__ __launch_bounds__(256) void norm_rope(unsigned short* __restrict__ Qhi,
                                                 unsigned short* __restrict__ Qlo,
                                                 unsigned short* __restrict__ Khi,
                                                 unsigned short* __restrict__ Klo,
                                                 const float* __restrict__ qw,
                                                 const float* __restrict__ kw) {
    const int lane = threadIdx.x & 63;
    const int widx = threadIdx.x >> 6;
    const int rid  = blockIdx.x * 4 + widx;        // bh*NN + t
    const bool isq = (blockIdx.y == 0);
    unsigned short* Ph = (isq ? Qhi : Khi);
    unsigned short* Pl = (isq ? Qlo : Klo);
    const float* w = isq ? qw : kw;
    const int t = rid % NN;
    size_t base = (size_t)rid * HD + lane;

    float v = bf2f(Ph[base]) + bf2f(Pl[base]);
    float ss = v * v;
#pragma unroll
    for (int o = 32; o; o >>= 1) ss += __shfl_xor(ss, o);
    float r = 1.0f / sqrtf(ss * (1.0f / 64.0f) + 1e-6f);
    v = v * r * w[lane];

    float partner = __shfl_xor(v, 32);
    if (t > 0) {
        int p   = t - 1;
        int pos = (lane < 32) ? (p & 31) : (p >> 5);
        int j   = lane & 15;
        float invf = exp2f((float)j * (-13.287712379549449f / 16.0f));
        float ang  = (float)pos * invf;
        float c = cosf(ang), sn = sinf(ang);
        float rh = (lane < 32) ? -partner : partner;
        v = v * c + rh * sn;
    }
    if (isq) v *= 0.125f;   // fold d^-0.5 into q
    unsigned short hb = f2bf(v);
    Ph[base] = hb;
    Pl[base] = f2bf(v - bf2f(hb));
}

// ---------------- K3: MFMA flash attention (bf16 hi/lo, fp32 accumulate) -----------
__global__ __launch_bounds__(256) void attn_mfma(
    const unsigned short* __restrict__ Qhi, const unsigned short* __restrict__ Qlo,
    const unsigned short* __restrict__ Khi, const unsigned short* __restrict__ Klo,
    const unsigned short* __restrict__ Vth, const unsigned short* __restrict__ Vtl,
    float* __restrict__ O) {
    __shared__ __align__(16) char smem[49152];
    const int tid = threadIdx.x;
    const int lane = tid & 63, wv = tid >> 6;

    // XCD-aware remap: all 17 q-blocks of one bh land on one XCD (K/V L2 reuse)
    int lin = blockIdx.x;                  // 0..3263
    int xcd = lin & 7, loc = lin >> 3;     // loc 0..407
    int bh  = (loc / 17) * 8 + xcd;        // 0..191
    int qb  = loc - (loc / 17) * 17;       // 0..16
    const int q0 = qb * 64;

    const size_t kbase0 = (size_t)bh * NN * HD;
    const size_t vbase0 = (size_t)bh * HD * NNP;

    // Q A-fragments (held in regs for all tiles): row = lane&15, k = (lane>>4)*8..
    short8 qfh[2], qfl[2];
    {
        int qr = imin(q0 + (wv << 4) + (lane & 15), NN - 1);
        const unsigned short* qp  = Qhi + kbase0 + (size_t)qr * HD + ((lane >> 4) << 3);
        const unsigned short* qp2 = Qlo + kbase0 + (size_t)qr * HD + ((lane >> 4) << 3);
        qfh[0] = *(const short8*)(qp);
        qfh[1] = *(const short8*)(qp + 32);
        qfl[0] = *(const short8*)(qp2);
        qfl[1] = *(const short8*)(qp2 + 32);
    }

    f32x4 oa[4];
    const f32x4 fz = {0.f, 0.f, 0.f, 0.f};
#pragma unroll
    for (int db = 0; db < 4; ++db) oa[db] = fz;
    float m[4]    = {-INFINITY, -INFINITY, -INFINITY, -INFINITY};
    float lsum[4] = {0.f, 0.f, 0.f, 0.f};

    const int PB = 32768 + wv * 4096;      // per-wave P planes (hi @+0, lo @+2048)

    for (int j0 = 0; j0 < NN; j0 += 64) {
        // ---- stage K (rows=key) and V^T (rows=d) hi/lo tiles, XOR-swizzled ----
#pragma unroll
        for (int i = 0; i < 2; ++i) {
            int row = (wv << 4) + (i << 3) + (lane >> 3);   // 0..63 across block
            int g   = lane & 7;
            int off = row * 128 + (((g << 4)) ^ ((row & 7) << 4));
            int krow = imin(j0 + row, NN - 1);
            *(short8*)(smem + off)         = *(const short8*)(Khi + kbase0 + (size_t)krow * HD + (g << 3));
            *(short8*)(smem + 8192 + off)  = *(const short8*)(Klo + kbase0 + (size_t)krow * HD + (g << 3));
            int k0 = j0 + (g << 3);
            if (k0 > 1024) k0 = 1024;       // keep 16B read inside padded row; pads are 0
            *(short8*)(smem + 16384 + off) = *(const short8*)(Vth + vbase0 + (size_t)row * NNP + k0);
            *(short8*)(smem + 24576 + off) = *(const short8*)(Vtl + vbase0 + (size_t)row * NNP + k0);
        }
        __syncthreads();

        // ---- S = Q·K^T (hi/lo: 3 products) ----
        f32x4 sc[4];
#pragma unroll
        for (int c = 0; c < 4; ++c) sc[c] = fz;
#pragma unroll
        for (int ks = 0; ks < 2; ++ks) {
#pragma unroll
            for (int c = 0; c < 4; ++c) {
                int row  = (c << 4) + (lane & 15);
                int boff = row * 128 + (((ks << 6) + ((lane >> 4) << 4)) ^ ((row & 7) << 4));
                short8 kfh = *(const short8*)(smem + boff);
                short8 kfl = *(const short8*)(smem + 8192 + boff);
                sc[c] = __builtin_amdgcn_mfma_f32_16x16x32_bf16(qfh[ks], kfh, sc[c], 0, 0, 0);
                sc[c] = __builtin_amdgcn_mfma_f32_16x16x32_bf16(qfh[ks], kfl, sc[c], 0, 0, 0);
                sc[c] = __builtin_amdgcn_mfma_f32_16x16x32_bf16(qfl[ks], kfh, sc[c], 0, 0, 0);
            }
        }

        // ---- mask tail keys ----
        int kq = j0 + (lane & 15);
        const f32x4 fneg = {-1e30f, -1e30f, -1e30f, -1e30f};
#pragma unroll
        for (int c = 0; c < 4; ++c)
            if (kq + (c << 4) >= NN) sc[c] = fneg;

        // ---- online softmax on C-frag layout; write P planes (swizzled) ----
#pragma unroll
        for (int r = 0; r < 4; ++r) {
            float rm = fmaxf(fmaxf(sc[0][r], sc[1][r]), fmaxf(sc[2][r], sc[3][r]));
            rm = fmaxf(rm, __shfl_xor(rm, 1));
            rm = fmaxf(rm, __shfl_xor(rm, 2));
            rm = fmaxf(rm, __shfl_xor(rm, 4));
            rm = fmaxf(rm, __shfl_xor(rm, 8));
            float mnew = fmaxf(m[r], rm);
            float corr = __expf(m[r] - mnew);
            m[r] = mnew;
            int prow  = ((lane >> 4) << 2) + r;
            int rowsw = (prow & 7) << 4;
            float rs = 0.f;
#pragma unroll
            for (int c = 0; c < 4; ++c) {
                float p = __expf(sc[c][r] - mnew);
                rs += p;
                unsigned short ph = f2bf(p);
                unsigned short pl = f2bf(p - bf2f(ph));
                int colb = ((c << 4) + (lane & 15)) << 1;
                int off  = PB + prow * 128 + (colb ^ rowsw);
                *(unsigned short*)(smem + off)        = ph;
                *(unsigned short*)(smem + off + 2048) = pl;
            }
            rs += __shfl_xor(rs, 1);
            rs += __shfl_xor(rs, 2);
            rs += __shfl_xor(rs, 4);
            rs += __shfl_xor(rs, 8);
            lsum[r] = lsum[r] * corr + rs;
#pragma unroll
            for (int db = 0; db < 4; ++db) oa[db][r] *= corr;
        }

        // ---- O += P·V (hi/lo: 3 products), B-frags from V^T tile ----
#pragma unroll
        for (int ks = 0; ks < 2; ++ks) {
            int prow = lane & 15;
            int poff = PB + prow * 128 + (((ks << 6) + ((lane >> 4) << 4)) ^ ((prow & 7) << 4));
            short8 pah = *(const short8*)(smem + poff);
            short8 pal = *(const short8*)(smem + poff + 2048);
#pragma unroll
            for (int db = 0; db < 4; ++db) {
                int vrow = (db << 4) + (lane & 15);
                int voff = vrow * 128 + (((ks << 6) + ((lane >> 4) << 4)) ^ ((vrow & 7) << 4));
                short8 vfh = *(const short8*)(smem + 16384 + voff);
                short8 vfl = *(const short8*)(smem + 24576 + voff);
                oa[db] = __builtin_amdgcn_mfma_f32_16x16x32_bf16(pah, vfh, oa[db], 0, 0, 0);
                oa[db] = __builtin_amdgcn_mfma_f32_16x16x32_bf16(pah, vfl, oa[db], 0, 0, 0);
                oa[db] = __builtin_amdgcn_mfma_f32_16x16x32_bf16(pal, vfh, oa[db], 0, 0, 0);
            }
        }
        __syncthreads();
    }

    // ---- store O[b][q][h*64+d] ----
    const int b = bh / NHEADS, h = bh - b * NHEADS;
#pragma unroll
    for (int r = 0; r < 4; ++r) {
        int q = q0 + (wv << 4) + ((lane >> 4) << 2) + r;
        if (q < NN) {
            float inv = 1.0f / lsum[r];
#pragma unroll
            for (int db = 0; db < 4; ++db) {
                int d = (db << 4) + (lane & 15);
                O[((size_t)b * NN + q) * CC + h * HD + d] = oa[db][r] * inv;
            }
        }
    }
}

// ---------------- K4: output projection GEMM + bias (VALU fp32) --------------------
__global__ __launch_bounds__(256) void proj_gemm(const float* __restrict__ A,
                                                 const float* __restrict__ Bw,
                                                 const float* __restrict__ bias,
                                                 float* __restrict__ out) {
    __shared__ float As[16][68];
    __shared__ float Bs[16][68];
    const int tid = threadIdx.x;
    const int tx = tid & 15, ty = tid >> 4;
    const int m0 = blockIdx.x * 64;
    const int n0 = blockIdx.y * 64;

    const int ar = tid >> 2;
    const int ak = (tid & 3) * 4;
    const int br = tid >> 4;
    const int bc = (tid & 15) * 4;

    const float* Aptr = A + (size_t)imin(m0 + ar, MM - 1) * CC;
    float acc[4][4] = {};

    for (int k0 = 0; k0 < CC; k0 += 16) {
        float4 a = *(const float4*)(Aptr + k0 + ak);
        float4 b = *(const float4*)(Bw + (size_t)(k0 + br) * CC + n0 + bc);
        As[ak + 0][ar] = a.x; As[ak + 1][ar] = a.y;
        As[ak + 2][ar] = a.z; As[ak + 3][ar] = a.w;
        *(float4*)&Bs[br][bc] = b;
        __syncthreads();
#pragma unroll
        for (int k = 0; k < 16; ++k) {
            float4 av = *(const float4*)&As[k][ty * 4];
            float4 bv = *(const float4*)&Bs[k][tx * 4];
            float aa[4] = {av.x, av.y, av.z, av.w};
            float bb[4] = {bv.x, bv.y, bv.z, bv.w};
#pragma unroll
            for (int r = 0; r < 4; ++r)
#pragma unroll
                for (int c = 0; c < 4; ++c) acc[r][c] = fmaf(aa[r], bb[c], acc[r][c]);
        }
        __syncthreads();
    }
#pragma unroll
    for (int r = 0; r < 4; ++r) {
        int m = m0 + ty * 4 + r;
        if (m < MM) {
            int n = n0 + tx * 4;
            float4 o = {acc[r][0] + bias[n + 0], acc[r][1] + bias[n + 1],
                        acc[r][2] + bias[n + 2], acc[r][3] + bias[n + 3]};
            *(float4*)(out + (size_t)m * CC + n) = o;
        }
    }
}

extern "C" void kernel_launch(void* const* d_in, const int* in_sizes, int n_in,
                              void* d_out, int out_size, void* d_ws, size_t ws_size,
                              hipStream_t stream) {
    const float* x      = (const float*)d_in[0];
    const float* qkv_w  = (const float*)d_in[1];
    const float* proj_w = (const float*)d_in[2];
    const float* proj_b = (const float*)d_in[3];
    const float* qnw    = (const float*)d_in[4];
    const float* knw    = (const float*)d_in[5];

    unsigned short* us = (unsigned short*)d_ws;
    unsigned short* Qhi = us;
    unsigned short* Qlo = us + QSZ;
    unsigned short* Khi = us + 2 * QSZ;
    unsigned short* Klo = us + 3 * QSZ;
    unsigned short* Vth = us + 4 * QSZ;
    unsigned short* Vtl = us + 4 * QSZ + VTSZ;
    float* O = (float*)(us + 4 * QSZ + 2 * VTSZ);

    qkv_gemm<<<dim3((MM + 63) / 64, 36), 256, 0, stream>>>(x, qkv_w, Qhi, Qlo, Khi, Klo, Vth, Vtl);
    norm_rope<<<dim3(BB * NHEADS * NN / 4, 2), 256, 0, stream>>>(Qhi, Qlo, Khi, Klo, qnw, knw);
    attn_mfma<<<dim3(8 * 408), 256, 0, stream>>>(Qhi, Qlo, Khi, Klo, Vth, Vtl, O);
    proj_gemm<<<dim3((MM + 63) / 64, CC / 64), 256, 0, stream>>>(O, proj_w, proj_b, (float*)d_out);
}

// Round 5
// 860.988 us; speedup vs baseline: 2.3416x; 1.7672x over previous
//
#include <hip/hip_runtime.h>
#include <math.h>

#define NHEADS 12
#define HD 64
#define BB 16
#define NN 1025
#define CC 768
#define MM (BB * NN)                       // 16400
#define QSZ ((size_t)BB * NHEADS * NN * HD)   // 12,595,200
#define NNP 1032                           // padded t-stride for V^T
#define VTSZ ((size_t)BB * NHEADS * HD * NNP)
#define XSZ  ((size_t)MM * CC)             // 12,595,200
#define WTSZ ((size_t)CC * 3 * CC)         // 1,769,472
#define PWSZ ((size_t)CC * CC)             // 589,824

typedef __attribute__((ext_vector_type(8))) short short8;
typedef __attribute__((ext_vector_type(4))) float f32x4;
typedef __attribute__((ext_vector_type(4))) unsigned short us4;
typedef unsigned short us;

__device__ __forceinline__ int imin(int a, int b) { return a < b ? a : b; }

__device__ __forceinline__ us f2bf(float f) {   // RTNE fp32->bf16 bits
    unsigned u = __float_as_uint(f);
    u += 0x7FFF + ((u >> 16) & 1);
    return (us)(u >> 16);
}
__device__ __forceinline__ float bf2f(us b) {
    return __uint_as_float(((unsigned)b) << 16);
}

// ---------------- split_x: fp32 -> bf16 hi/lo planes -------------------------------
__global__ __launch_bounds__(256) void split_x(const float* __restrict__ src,
                                               us* __restrict__ hi, us* __restrict__ lo) {
    size_t i = ((size_t)blockIdx.x * 256 + threadIdx.x) * 8;
    float4 a = *(const float4*)(src + i);
    float4 b = *(const float4*)(src + i + 4);
    float v[8] = {a.x, a.y, a.z, a.w, b.x, b.y, b.z, b.w};
    short8 h, l;
#pragma unroll
    for (int j = 0; j < 8; ++j) {
        us hb = f2bf(v[j]);
        h[j] = (short)hb;
        l[j] = (short)f2bf(v[j] - bf2f(hb));
    }
    *(short8*)(hi + i) = h;
    *(short8*)(lo + i) = l;
}

// ---------------- tsplit: W [K][N] fp32 -> W^T hi/lo [N][K] bf16 -------------------
__global__ __launch_bounds__(256) void tsplit(const float* __restrict__ w,
                                              us* __restrict__ thi, us* __restrict__ tlo,
                                              int K, int N) {
    __shared__ float tile[64][65];
    const int t = threadIdx.x;
    const int n0 = blockIdx.x * 64, k0 = blockIdx.y * 64;
    {
        int kr = t & 63, so = t >> 6;        // 4 float4 per thread
#pragma unroll
        for (int g = 0; g < 4; ++g) {
            int c = (so * 4 + g) * 4;
            float4 v = *(const float4*)(w + (size_t)(k0 + kr) * N + n0 + c);
            tile[kr][c + 0] = v.x; tile[kr][c + 1] = v.y;
            tile[kr][c + 2] = v.z; tile[kr][c + 3] = v.w;
        }
    }
    __syncthreads();
    int nr = t & 63, half = t >> 6;          // 16 k-values per thread
    short8 h0, l0, h1, l1;
#pragma unroll
    for (int j = 0; j < 8; ++j) {
        float v = tile[half * 16 + j][nr];
        us hb = f2bf(v);
        h0[j] = (short)hb; l0[j] = (short)f2bf(v - bf2f(hb));
    }
#pragma unroll
    for (int j = 0; j < 8; ++j) {
        float v = tile[half * 16 + 8 + j][nr];
        us hb = f2bf(v);
        h1[j] = (short)hb; l1[j] = (short)f2bf(v - bf2f(hb));
    }
    size_t o = (size_t)(n0 + nr) * K + k0 + half * 16;
    *(short8*)(thi + o) = h0; *(short8*)(thi + o + 8) = h1;
    *(short8*)(tlo + o) = l0; *(short8*)(tlo + o + 8) = l1;
}

// ---------------- gemm_mfma: [N][768]^T-planes x [M][768]-planes -------------------
// D row = n (A free dim), col = m (B free dim). MODE 0: qkv epilogue; MODE 1: proj.
template<int MODE>
__global__ __launch_bounds__(256) void gemm_mfma(
    const us* __restrict__ Ahi, const us* __restrict__ Alo,   // W^T planes [N][768]
    const us* __restrict__ Bhi, const us* __restrict__ Blo,   // X/O planes [M][768]
    us* __restrict__ Qhi, us* __restrict__ Qlo,
    us* __restrict__ Khi, us* __restrict__ Klo,
    us* __restrict__ Vth, us* __restrict__ Vtl,
    float* __restrict__ fout, const float* __restrict__ bias) {
    __shared__ __align__(16) char lds[36864];
    char* ldsA = lds;
    char* ldsB = lds + 18432;
    const int tid = threadIdx.x;
    const int lane = tid & 63, wv = tid >> 6;
    const int wn = wv >> 1, wm = wv & 1;
    const int n0 = blockIdx.x * 128, m0 = blockIdx.y * 128;

    f32x4 acc[4][4];
    const f32x4 fz = {0.f, 0.f, 0.f, 0.f};
#pragma unroll
    for (int a = 0; a < 4; ++a)
#pragma unroll
        for (int b = 0; b < 4; ++b) acc[a][b] = fz;

    const int srow = tid & 127, pl = tid >> 7;      // staging: one row, one plane
    const us* baseA = (pl ? Alo : Ahi) + (size_t)(n0 + srow) * CC;
    const us* baseB = (pl ? Blo : Bhi) + (size_t)imin(m0 + srow, MM - 1) * CC;
    char* dstA = ldsA + srow * 144 + pl * 64;
    char* dstB = ldsB + srow * 144 + pl * 64;

    for (int k0 = 0; k0 < CC; k0 += 32) {
#pragma unroll
        for (int c = 0; c < 4; ++c)
            *(short8*)(dstA + c * 16) = *(const short8*)(baseA + k0 + c * 8);
#pragma unroll
        for (int c = 0; c < 4; ++c)
            *(short8*)(dstB + c * 16) = *(const short8*)(baseB + k0 + c * 8);
        __syncthreads();

        short8 af[4][2];
#pragma unroll
        for (int nc = 0; nc < 4; ++nc) {
            int ra = wn * 64 + nc * 16 + (lane & 15);
            const char* pa = ldsA + ra * 144 + ((lane >> 4) << 4);
            af[nc][0] = *(const short8*)pa;
            af[nc][1] = *(const short8*)(pa + 64);
        }
#pragma unroll
        for (int mc = 0; mc < 4; ++mc) {
            int rb = wm * 64 + mc * 16 + (lane & 15);
            const char* pb = ldsB + rb * 144 + ((lane >> 4) << 4);
            short8 b0 = *(const short8*)pb;
            short8 b1 = *(const short8*)(pb + 64);
#pragma unroll
            for (int nc = 0; nc < 4; ++nc) {
                acc[nc][mc] = __builtin_amdgcn_mfma_f32_16x16x32_bf16(af[nc][0], b0, acc[nc][mc], 0, 0, 0);
                acc[nc][mc] = __builtin_amdgcn_mfma_f32_16x16x32_bf16(af[nc][0], b1, acc[nc][mc], 0, 0, 0);
                acc[nc][mc] = __builtin_amdgcn_mfma_f32_16x16x32_bf16(af[nc][1], b0, acc[nc][mc], 0, 0, 0);
            }
        }
        __syncthreads();
    }

    // ---- epilogue ----
#pragma unroll
    for (int mc = 0; mc < 4; ++mc) {
        int m = m0 + wm * 64 + mc * 16 + (lane & 15);
        if (m >= MM) continue;
        if (MODE == 0) {
            int b = m / NN, t = m - b * NN;
#pragma unroll
            for (int nc = 0; nc < 4; ++nc) {
                int n = n0 + wn * 64 + nc * 16 + ((lane >> 4) << 2);
                int s = n0 / CC;                    // tile never straddles tensors
                int nin = n - s * CC;
                int head = nin >> 6, d0 = nin & 63;
                int bh = b * NHEADS + head;
                if (s < 2) {
                    us4 h4, l4;
#pragma unroll
                    for (int r = 0; r < 4; ++r) {
                        float v = acc[nc][mc][r];
                        us hb = f2bf(v);
                        h4[r] = hb; l4[r] = f2bf(v - bf2f(hb));
                    }
                    size_t idx = ((size_t)bh * NN + t) * HD + d0;
                    if (s == 0) { *(us4*)(Qhi + idx) = h4; *(us4*)(Qlo + idx) = l4; }
                    else        { *(us4*)(Khi + idx) = h4; *(us4*)(Klo + idx) = l4; }
                } else {
#pragma unroll
                    for (int r = 0; r < 4; ++r) {
                        float v = acc[nc][mc][r];
                        us hb = f2bf(v);
                        us lb = f2bf(v - bf2f(hb));
                        size_t idx = ((size_t)bh * HD + d0 + r) * NNP + t;
                        Vth[idx] = hb;
                        Vtl[idx] = lb;
                        if (t == NN - 1) {
#pragma unroll
                            for (int tt = 1; tt <= 7; ++tt) { Vth[idx + tt] = 0; Vtl[idx + tt] = 0; }
                        }
                    }
                }
            }
        } else {
#pragma unroll
            for (int nc = 0; nc < 4; ++nc) {
                int n = n0 + wn * 64 + nc * 16 + ((lane >> 4) << 2);
                float4 o = {acc[nc][mc][0] + bias[n + 0], acc[nc][mc][1] + bias[n + 1],
                            acc[nc][mc][2] + bias[n + 2], acc[nc][mc][3] + bias[n + 3]};
                *(float4*)(fout + (size_t)m * CC + n) = o;
            }
        }
    }
}

// ---------------- norm_rope (unchanged) --------------------------------------------
__global__ __launch_bounds__(256) void norm_rope(us* __restrict__ Qhi, us* __restrict__ Qlo,
                                                 us* __restrict__ Khi, us* __restrict__ Klo,
                                                 const float* __restrict__ qw,
                                                 const float* __restrict__ kw) {
    const int lane = threadIdx.x & 63;
    const int widx = threadIdx.x >> 6;
    const int rid  = blockIdx.x * 4 + widx;
    const bool isq = (blockIdx.y == 0);
    us* Ph = (isq ? Qhi : Khi);
    us* Pl = (isq ? Qlo : Klo);
    const float* w = isq ? qw : kw;
    const int t = rid % NN;
    size_t base = (size_t)rid * HD + lane;

    float v = bf2f(Ph[base]) + bf2f(Pl[base]);
    float ss = v * v;
#pragma unroll
    for (int o = 32; o; o >>= 1) ss += __shfl_xor(ss, o);
    float r = 1.0f / sqrtf(ss * (1.0f / 64.0f) + 1e-6f);
    v = v * r * w[lane];

    float partner = __shfl_xor(v, 32);
    if (t > 0) {
        int p   = t - 1;
        int pos = (lane < 32) ? (p & 31) : (p >> 5);
        int j   = lane & 15;
        float invf = exp2f((float)j * (-13.287712379549449f / 16.0f));
        float ang  = (float)pos * invf;
        float c = cosf(ang), sn = sinf(ang);
        float rh = (lane < 32) ? -partner : partner;
        v = v * c + rh * sn;
    }
    if (isq) v *= 0.125f;
    us hb = f2bf(v);
    Ph[base] = hb;
    Pl[base] = f2bf(v - bf2f(hb));
}

// ---------------- attn: MFMA flash attention; epilogue -> O hi/lo planes -----------
__global__ __launch_bounds__(256) void attn_mfma(
    const us* __restrict__ Qhi, const us* __restrict__ Qlo,
    const us* __restrict__ Khi, const us* __restrict__ Klo,
    const us* __restrict__ Vth, const us* __restrict__ Vtl,
    us* __restrict__ Ohi, us* __restrict__ Olo) {
    __shared__ __align__(16) char smem[49152];
    const int tid = threadIdx.x;
    const int lane = tid & 63, wv = tid >> 6;

    int lin = blockIdx.x;
    int xcd = lin & 7, loc = lin >> 3;
    int bh  = (loc / 17) * 8 + xcd;
    int qb  = loc - (loc / 17) * 17;
    const int q0 = qb * 64;

    const size_t kbase0 = (size_t)bh * NN * HD;
    const size_t vbase0 = (size_t)bh * HD * NNP;

    short8 qfh[2], qfl[2];
    {
        int qr = imin(q0 + (wv << 4) + (lane & 15), NN - 1);
        const us* qp  = Qhi + kbase0 + (size_t)qr * HD + ((lane >> 4) << 3);
        const us* qp2 = Qlo + kbase0 + (size_t)qr * HD + ((lane >> 4) << 3);
        qfh[0] = *(const short8*)(qp);
        qfh[1] = *(const short8*)(qp + 32);
        qfl[0] = *(const short8*)(qp2);
        qfl[1] = *(const short8*)(qp2 + 32);
    }

    f32x4 oa[4];
    const f32x4 fz = {0.f, 0.f, 0.f, 0.f};
#pragma unroll
    for (int db = 0; db < 4; ++db) oa[db] = fz;
    float m[4]    = {-INFINITY, -INFINITY, -INFINITY, -INFINITY};
    float lsum[4] = {0.f, 0.f, 0.f, 0.f};

    const int PB = 32768 + wv * 4096;

    for (int j0 = 0; j0 < NN; j0 += 64) {
#pragma unroll
        for (int i = 0; i < 2; ++i) {
            int row = (wv << 4) + (i << 3) + (lane >> 3);
            int g   = lane & 7;
            int off = row * 128 + (((g << 4)) ^ ((row & 7) << 4));
            int krow = imin(j0 + row, NN - 1);
            *(short8*)(smem + off)         = *(const short8*)(Khi + kbase0 + (size_t)krow * HD + (g << 3));
            *(short8*)(smem + 8192 + off)  = *(const short8*)(Klo + kbase0 + (size_t)krow * HD + (g << 3));
            int k0 = j0 + (g << 3);
            if (k0 > 1024) k0 = 1024;
            *(short8*)(smem + 16384 + off) = *(const short8*)(Vth + vbase0 + (size_t)row * NNP + k0);
            *(short8*)(smem + 24576 + off) = *(const short8*)(Vtl + vbase0 + (size_t)row * NNP + k0);
        }
        __syncthreads();

        f32x4 sc[4];
#pragma unroll
        for (int c = 0; c < 4; ++c) sc[c] = fz;
#pragma unroll
        for (int ks = 0; ks < 2; ++ks) {
#pragma unroll
            for (int c = 0; c < 4; ++c) {
                int row  = (c << 4) + (lane & 15);
                int boff = row * 128 + (((ks << 6) + ((lane >> 4) << 4)) ^ ((row & 7) << 4));
                short8 kfh = *(const short8*)(smem + boff);
                short8 kfl = *(const short8*)(smem + 8192 + boff);
                sc[c] = __builtin_amdgcn_mfma_f32_16x16x32_bf16(qfh[ks], kfh, sc[c], 0, 0, 0);
                sc[c] = __builtin_amdgcn_mfma_f32_16x16x32_bf16(qfh[ks], kfl, sc[c], 0, 0, 0);
                sc[c] = __builtin_amdgcn_mfma_f32_16x16x32_bf16(qfl[ks], kfh, sc[c], 0, 0, 0);
            }
        }

        int kq = j0 + (lane & 15);
        const f32x4 fneg = {-1e30f, -1e30f, -1e30f, -1e30f};
#pragma unroll
        for (int c = 0; c < 4; ++c)
            if (kq + (c << 4) >= NN) sc[c] = fneg;

#pragma unroll
        for (int r = 0; r < 4; ++r) {
            float rm = fmaxf(fmaxf(sc[0][r], sc[1][r]), fmaxf(sc[2][r], sc[3][r]));
            rm = fmaxf(rm, __shfl_xor(rm, 1));
            rm = fmaxf(rm, __shfl_xor(rm, 2));
            rm = fmaxf(rm, __shfl_xor(rm, 4));
            rm = fmaxf(rm, __shfl_xor(rm, 8));
            float mnew = fmaxf(m[r], rm);
            float corr = __expf(m[r] - mnew);
            m[r] = mnew;
            int prow  = ((lane >> 4) << 2) + r;
            int rowsw = (prow & 7) << 4;
            float rs = 0.f;
#pragma unroll
            for (int c = 0; c < 4; ++c) {
                float p = __expf(sc[c][r] - mnew);
                rs += p;
                us ph = f2bf(p);
                us plo = f2bf(p - bf2f(ph));
                int colb = ((c << 4) + (lane & 15)) << 1;
                int off  = PB + prow * 128 + (colb ^ rowsw);
                *(us*)(smem + off)        = ph;
                *(us*)(smem + off + 2048) = plo;
            }
            rs += __shfl_xor(rs, 1);
            rs += __shfl_xor(rs, 2);
            rs += __shfl_xor(rs, 4);
            rs += __shfl_xor(rs, 8);
            lsum[r] = lsum[r] * corr + rs;
#pragma unroll
            for (int db = 0; db < 4; ++db) oa[db][r] *= corr;
        }

#pragma unroll
        for (int ks = 0; ks < 2; ++ks) {
            int prow = lane & 15;
            int poff = PB + prow * 128 + (((ks << 6) + ((lane >> 4) << 4)) ^ ((prow & 7) << 4));
            short8 pah = *(const short8*)(smem + poff);
            short8 pal = *(const short8*)(smem + poff + 2048);
#pragma unroll
            for (int db = 0; db < 4; ++db) {
                int vrow = (db << 4) + (lane & 15);
                int voff = vrow * 128 + (((ks << 6) + ((lane >> 4) << 4)) ^ ((vrow & 7) << 4));
                short8 vfh = *(const short8*)(smem + 16384 + voff);
                short8 vfl = *(const short8*)(smem + 24576 + voff);
                oa[db] = __builtin_amdgcn_mfma_f32_16x16x32_bf16(pah, vfh, oa[db], 0, 0, 0);
                oa[db] = __builtin_amdgcn_mfma_f32_16x16x32_bf16(pah, vfl, oa[db], 0, 0, 0);
                oa[db] = __builtin_amdgcn_mfma_f32_16x16x32_bf16(pal, vfh, oa[db], 0, 0, 0);
            }
        }
        __syncthreads();
    }

    const int b = bh / NHEADS, h = bh - b * NHEADS;
#pragma unroll
    for (int r = 0; r < 4; ++r) {
        int q = q0 + (wv << 4) + ((lane >> 4) << 2) + r;
        if (q < NN) {
            float inv = 1.0f / lsum[r];
#pragma unroll
            for (int db = 0; db < 4; ++db) {
                int d = (db << 4) + (lane & 15);
                float v = oa[db][r] * inv;
                size_t idx = ((size_t)b * NN + q) * CC + h * HD + d;
                us hb = f2bf(v);
                Ohi[idx] = hb;
                Olo[idx] = f2bf(v - bf2f(hb));
            }
        }
    }
}

extern "C" void kernel_launch(void* const* d_in, const int* in_sizes, int n_in,
                              void* d_out, int out_size, void* d_ws, size_t ws_size,
                              hipStream_t stream) {
    const float* x      = (const float*)d_in[0];
    const float* qkv_w  = (const float*)d_in[1];
    const float* proj_w = (const float*)d_in[2];
    const float* proj_b = (const float*)d_in[3];
    const float* qnw    = (const float*)d_in[4];
    const float* knw    = (const float*)d_in[5];

    us* p = (us*)d_ws;
    us* Qhi = p;                 p += QSZ;
    us* Qlo = p;                 p += QSZ;
    us* Khi = p;                 p += QSZ;
    us* Klo = p;                 p += QSZ;
    us* Vth = p;                 p += VTSZ;
    us* Vtl = p;                 p += VTSZ;
    us* Xhi = p;                 p += XSZ;   // reused as Ohi after qkv GEMM
    us* Xlo = p;                 p += XSZ;   // reused as Olo
    us* Wthi = p;                p += WTSZ;
    us* Wtlo = p;                p += WTSZ;
    us* Pwhi = p;                p += PWSZ;
    us* Pwlo = p;                p += PWSZ;

    split_x<<<dim3((int)(XSZ / 8 / 256)), 256, 0, stream>>>(x, Xhi, Xlo);
    tsplit<<<dim3(3 * CC / 64, CC / 64), 256, 0, stream>>>(qkv_w, Wthi, Wtlo, CC, 3 * CC);
    tsplit<<<dim3(CC / 64, CC / 64), 256, 0, stream>>>(proj_w, Pwhi, Pwlo, CC, CC);

    gemm_mfma<0><<<dim3(3 * CC / 128, (MM + 127) / 128), 256, 0, stream>>>(
        Wthi, Wtlo, Xhi, Xlo, Qhi, Qlo, Khi, Klo, Vth, Vtl, nullptr, nullptr);
    norm_rope<<<dim3(BB * NHEADS * NN / 4, 2), 256, 0, stream>>>(Qhi, Qlo, Khi, Klo, qnw, knw);
    attn_mfma<<<dim3(8 * 408), 256, 0, stream>>>(Qhi, Qlo, Khi, Klo, Vth, Vtl, Xhi, Xlo);
    gemm_mfma<1><<<dim3(CC / 128, (MM + 127) / 128), 256, 0, stream>>>(
        Pwhi, Pwlo, Xhi, Xlo, nullptr, nullptr, nullptr, nullptr, nullptr, nullptr,
        (float*)d_out, proj_b);
}

// Round 6
// 665.452 us; speedup vs baseline: 3.0297x; 1.2938x over previous
//
#include <hip/hip_runtime.h>
#include <math.h>

#define NHEADS 12
#define HD 64
#define BB 16
#define NN 1025
#define CC 768
#define MM (BB * NN)                       // 16400
#define QSZ ((size_t)BB * NHEADS * NN * HD)   // 12,595,200
#define NNP 1032                           // padded t-stride for V^T
#define VTSZ ((size_t)BB * NHEADS * HD * NNP)
#define XSZ  ((size_t)MM * CC)             // 12,595,200
#define WTSZ ((size_t)CC * 3 * CC)         // 1,769,472
#define PWSZ ((size_t)CC * CC)             // 589,824

typedef __attribute__((ext_vector_type(8))) short short8;
typedef __attribute__((ext_vector_type(4))) float f32x4;
typedef __attribute__((ext_vector_type(4))) unsigned short us4;
typedef unsigned short us;

__device__ __forceinline__ int imin(int a, int b) { return a < b ? a : b; }

__device__ __forceinline__ us f2bf(float f) {   // RTNE fp32->bf16 bits
    unsigned u = __float_as_uint(f);
    u += 0x7FFF + ((u >> 16) & 1);
    return (us)(u >> 16);
}
__device__ __forceinline__ float bf2f(us b) {
    return __uint_as_float(((unsigned)b) << 16);
}

// ---------------- split_x: fp32 -> bf16 hi/lo planes -------------------------------
__global__ __launch_bounds__(256) void split_x(const float* __restrict__ src,
                                               us* __restrict__ hi, us* __restrict__ lo) {
    size_t i = ((size_t)blockIdx.x * 256 + threadIdx.x) * 8;
    float4 a = *(const float4*)(src + i);
    float4 b = *(const float4*)(src + i + 4);
    float v[8] = {a.x, a.y, a.z, a.w, b.x, b.y, b.z, b.w};
    short8 h, l;
#pragma unroll
    for (int j = 0; j < 8; ++j) {
        us hb = f2bf(v[j]);
        h[j] = (short)hb;
        l[j] = (short)f2bf(v[j] - bf2f(hb));
    }
    *(short8*)(hi + i) = h;
    *(short8*)(lo + i) = l;
}

// ---------------- tsplit: W [K][N] fp32 -> W^T hi/lo [N][K] bf16 -------------------
__global__ __launch_bounds__(256) void tsplit(const float* __restrict__ w,
                                              us* __restrict__ thi, us* __restrict__ tlo,
                                              int K, int N) {
    __shared__ float tile[64][65];
    const int t = threadIdx.x;
    const int n0 = blockIdx.x * 64, k0 = blockIdx.y * 64;
    {
        int kr = t & 63, so = t >> 6;
#pragma unroll
        for (int g = 0; g < 4; ++g) {
            int c = (so * 4 + g) * 4;
            float4 v = *(const float4*)(w + (size_t)(k0 + kr) * N + n0 + c);
            tile[kr][c + 0] = v.x; tile[kr][c + 1] = v.y;
            tile[kr][c + 2] = v.z; tile[kr][c + 3] = v.w;
        }
    }
    __syncthreads();
    int nr = t & 63, half = t >> 6;
    short8 h0, l0, h1, l1;
#pragma unroll
    for (int j = 0; j < 8; ++j) {
        float v = tile[half * 16 + j][nr];
        us hb = f2bf(v);
        h0[j] = (short)hb; l0[j] = (short)f2bf(v - bf2f(hb));
    }
#pragma unroll
    for (int j = 0; j < 8; ++j) {
        float v = tile[half * 16 + 8 + j][nr];
        us hb = f2bf(v);
        h1[j] = (short)hb; l1[j] = (short)f2bf(v - bf2f(hb));
    }
    size_t o = (size_t)(n0 + nr) * K + k0 + half * 16;
    *(short8*)(thi + o) = h0; *(short8*)(thi + o + 8) = h1;
    *(short8*)(tlo + o) = l0; *(short8*)(tlo + o + 8) = l1;
}

// ---------------- gemm_mfma: [N][768]^T-planes x [M][768]-planes -------------------
template<int MODE>
__global__ __launch_bounds__(256) void gemm_mfma(
    const us* __restrict__ Ahi, const us* __restrict__ Alo,
    const us* __restrict__ Bhi, const us* __restrict__ Blo,
    us* __restrict__ Qhi, us* __restrict__ Qlo,
    us* __restrict__ Khi, us* __restrict__ Klo,
    us* __restrict__ Vth,
    float* __restrict__ fout, const float* __restrict__ bias) {
    __shared__ __align__(16) char lds[36864];
    char* ldsA = lds;
    char* ldsB = lds + 18432;
    const int tid = threadIdx.x;
    const int lane = tid & 63, wv = tid >> 6;
    const int wn = wv >> 1, wm = wv & 1;
    const int n0 = blockIdx.x * 128, m0 = blockIdx.y * 128;

    f32x4 acc[4][4];
    const f32x4 fz = {0.f, 0.f, 0.f, 0.f};
#pragma unroll
    for (int a = 0; a < 4; ++a)
#pragma unroll
        for (int b = 0; b < 4; ++b) acc[a][b] = fz;

    const int srow = tid & 127, pl = tid >> 7;
    const us* baseA = (pl ? Alo : Ahi) + (size_t)(n0 + srow) * CC;
    const us* baseB = (pl ? Blo : Bhi) + (size_t)imin(m0 + srow, MM - 1) * CC;
    char* dstA = ldsA + srow * 144 + pl * 64;
    char* dstB = ldsB + srow * 144 + pl * 64;

    for (int k0 = 0; k0 < CC; k0 += 32) {
#pragma unroll
        for (int c = 0; c < 4; ++c)
            *(short8*)(dstA + c * 16) = *(const short8*)(baseA + k0 + c * 8);
#pragma unroll
        for (int c = 0; c < 4; ++c)
            *(short8*)(dstB + c * 16) = *(const short8*)(baseB + k0 + c * 8);
        __syncthreads();

        short8 af[4][2];
#pragma unroll
        for (int nc = 0; nc < 4; ++nc) {
            int ra = wn * 64 + nc * 16 + (lane & 15);
            const char* pa = ldsA + ra * 144 + ((lane >> 4) << 4);
            af[nc][0] = *(const short8*)pa;
            af[nc][1] = *(const short8*)(pa + 64);
        }
#pragma unroll
        for (int mc = 0; mc < 4; ++mc) {
            int rb = wm * 64 + mc * 16 + (lane & 15);
            const char* pb = ldsB + rb * 144 + ((lane >> 4) << 4);
            short8 b0 = *(const short8*)pb;
            short8 b1 = *(const short8*)(pb + 64);
#pragma unroll
            for (int nc = 0; nc < 4; ++nc) {
                acc[nc][mc] = __builtin_amdgcn_mfma_f32_16x16x32_bf16(af[nc][0], b0, acc[nc][mc], 0, 0, 0);
                acc[nc][mc] = __builtin_amdgcn_mfma_f32_16x16x32_bf16(af[nc][0], b1, acc[nc][mc], 0, 0, 0);
                acc[nc][mc] = __builtin_amdgcn_mfma_f32_16x16x32_bf16(af[nc][1], b0, acc[nc][mc], 0, 0, 0);
            }
        }
        __syncthreads();
    }

#pragma unroll
    for (int mc = 0; mc < 4; ++mc) {
        int m = m0 + wm * 64 + mc * 16 + (lane & 15);
        if (m >= MM) continue;
        if (MODE == 0) {
            int b = m / NN, t = m - b * NN;
#pragma unroll
            for (int nc = 0; nc < 4; ++nc) {
                int n = n0 + wn * 64 + nc * 16 + ((lane >> 4) << 2);
                int s = n0 / CC;
                int nin = n - s * CC;
                int head = nin >> 6, d0 = nin & 63;
                int bh = b * NHEADS + head;
                if (s < 2) {
                    us4 h4, l4;
#pragma unroll
                    for (int r = 0; r < 4; ++r) {
                        float v = acc[nc][mc][r];
                        us hb = f2bf(v);
                        h4[r] = hb; l4[r] = f2bf(v - bf2f(hb));
                    }
                    size_t idx = ((size_t)bh * NN + t) * HD + d0;
                    if (s == 0) { *(us4*)(Qhi + idx) = h4; *(us4*)(Qlo + idx) = l4; }
                    else        { *(us4*)(Khi + idx) = h4; *(us4*)(Klo + idx) = l4; }
                } else {
#pragma unroll
                    for (int r = 0; r < 4; ++r) {
                        float v = acc[nc][mc][r];
                        size_t idx = ((size_t)bh * HD + d0 + r) * NNP + t;
                        Vth[idx] = f2bf(v);
                        if (t == NN - 1) {
#pragma unroll
                            for (int tt = 1; tt <= 7; ++tt) Vth[idx + tt] = 0;
                        }
                    }
                }
            }
        } else {
#pragma unroll
            for (int nc = 0; nc < 4; ++nc) {
                int n = n0 + wn * 64 + nc * 16 + ((lane >> 4) << 2);
                float4 o = {acc[nc][mc][0] + bias[n + 0], acc[nc][mc][1] + bias[n + 1],
                            acc[nc][mc][2] + bias[n + 2], acc[nc][mc][3] + bias[n + 3]};
                *(float4*)(fout + (size_t)m * CC + n) = o;
            }
        }
    }
}

// ---------------- norm_rope (unchanged) --------------------------------------------
__global__ __launch_bounds__(256) void norm_rope(us* __restrict__ Qhi, us* __restrict__ Qlo,
                                                 us* __restrict__ Khi, us* __restrict__ Klo,
                                                 const float* __restrict__ qw,
                                                 const float* __restrict__ kw) {
    const int lane = threadIdx.x & 63;
    const int widx = threadIdx.x >> 6;
    const int rid  = blockIdx.x * 4 + widx;
    const bool isq = (blockIdx.y == 0);
    us* Ph = (isq ? Qhi : Khi);
    us* Pl = (isq ? Qlo : Klo);
    const float* w = isq ? qw : kw;
    const int t = rid % NN;
    size_t base = (size_t)rid * HD + lane;

    float v = bf2f(Ph[base]) + bf2f(Pl[base]);
    float ss = v * v;
#pragma unroll
    for (int o = 32; o; o >>= 1) ss += __shfl_xor(ss, o);
    float r = 1.0f / sqrtf(ss * (1.0f / 64.0f) + 1e-6f);
    v = v * r * w[lane];

    float partner = __shfl_xor(v, 32);
    if (t > 0) {
        int p   = t - 1;
        int pos = (lane < 32) ? (p & 31) : (p >> 5);
        int j   = lane & 15;
        float invf = exp2f((float)j * (-13.287712379549449f / 16.0f));
        float ang  = (float)pos * invf;
        float c = cosf(ang), sn = sinf(ang);
        float rh = (lane < 32) ? -partner : partner;
        v = v * c + rh * sn;
    }
    if (isq) v *= 0.125f;
    us hb = f2bf(v);
    Ph[base] = hb;
    Pl[base] = f2bf(v - bf2f(hb));
}

// ---------------- attn: MFMA flash attention, reg-prefetch double-buffer -----------
// LDS 32KB: Khi[0] Klo[8K] Vth[16K] P-hi per wave [24K + wv*2K]. PV = 1 product.
__global__ __launch_bounds__(256, 4) void attn_mfma(
    const us* __restrict__ Qhi, const us* __restrict__ Qlo,
    const us* __restrict__ Khi, const us* __restrict__ Klo,
    const us* __restrict__ Vth,
    us* __restrict__ Ohi, us* __restrict__ Olo) {
    __shared__ __align__(16) char smem[32768];
    const int tid = threadIdx.x;
    const int lane = tid & 63, wv = tid >> 6;

    int lin = blockIdx.x;
    int xcd = lin & 7, loc = lin >> 3;
    int bh  = (loc / 17) * 8 + xcd;
    int qb  = loc - (loc / 17) * 17;
    const int q0 = qb * 64;

    const size_t kbase0 = (size_t)bh * NN * HD;
    const size_t vbase0 = (size_t)bh * HD * NNP;

    short8 qfh[2], qfl[2];
    {
        int qr = imin(q0 + (wv << 4) + (lane & 15), NN - 1);
        const us* qp  = Qhi + kbase0 + (size_t)qr * HD + ((lane >> 4) << 3);
        const us* qp2 = Qlo + kbase0 + (size_t)qr * HD + ((lane >> 4) << 3);
        qfh[0] = *(const short8*)(qp);
        qfh[1] = *(const short8*)(qp + 32);
        qfl[0] = *(const short8*)(qp2);
        qfl[1] = *(const short8*)(qp2 + 32);
    }

    f32x4 oa[4];
    const f32x4 fz = {0.f, 0.f, 0.f, 0.f};
#pragma unroll
    for (int db = 0; db < 4; ++db) oa[db] = fz;
    float m[4]    = {-INFINITY, -INFINITY, -INFINITY, -INFINITY};
    float lsum[4] = {0.f, 0.f, 0.f, 0.f};

    const int PB = 24576 + wv * 2048;

    // register prefetch buffers (one tile in flight)
    short8 pkh[2], pkl[2], pvh[2];
    const int srow = (wv << 4) + (lane >> 3);   // +0 / +8 via i
    const int g    = lane & 7;
    auto issue_loads = [&](int j0) {
#pragma unroll
        for (int i = 0; i < 2; ++i) {
            int row = srow + (i << 3);
            int krow = imin(j0 + row, NN - 1);
            pkh[i] = *(const short8*)(Khi + kbase0 + (size_t)krow * HD + (g << 3));
            pkl[i] = *(const short8*)(Klo + kbase0 + (size_t)krow * HD + (g << 3));
            int k0 = j0 + (g << 3);
            if (k0 > 1024) k0 = 1024;
            pvh[i] = *(const short8*)(Vth + vbase0 + (size_t)row * NNP + k0);
        }
    };
    issue_loads(0);

    for (int t = 0; t < 17; ++t) {
        const int j0 = t * 64;
        // ---- write prefetched tile to LDS (XOR-swizzled rows) ----
#pragma unroll
        for (int i = 0; i < 2; ++i) {
            int row = srow + (i << 3);
            int off = row * 128 + ((g << 4) ^ ((row & 7) << 4));
            *(short8*)(smem + off)         = pkh[i];
            *(short8*)(smem + 8192 + off)  = pkl[i];
            *(short8*)(smem + 16384 + off) = pvh[i];
        }
        __syncthreads();
        if (t < 16) issue_loads(j0 + 64);   // in flight across compute

        // ---- S = Q·K^T (3 hi/lo products) ----
        f32x4 sc[4];
#pragma unroll
        for (int c = 0; c < 4; ++c) sc[c] = fz;
        __builtin_amdgcn_s_setprio(1);
#pragma unroll
        for (int ks = 0; ks < 2; ++ks) {
#pragma unroll
            for (int c = 0; c < 4; ++c) {
                int row  = (c << 4) + (lane & 15);
                int boff = row * 128 + (((ks << 6) + ((lane >> 4) << 4)) ^ ((row & 7) << 4));
                short8 kfh = *(const short8*)(smem + boff);
                short8 kfl = *(const short8*)(smem + 8192 + boff);
                sc[c] = __builtin_amdgcn_mfma_f32_16x16x32_bf16(qfh[ks], kfh, sc[c], 0, 0, 0);
                sc[c] = __builtin_amdgcn_mfma_f32_16x16x32_bf16(qfh[ks], kfl, sc[c], 0, 0, 0);
                sc[c] = __builtin_amdgcn_mfma_f32_16x16x32_bf16(qfl[ks], kfh, sc[c], 0, 0, 0);
            }
        }
        __builtin_amdgcn_s_setprio(0);

        int kq = j0 + (lane & 15);
        const f32x4 fneg = {-1e30f, -1e30f, -1e30f, -1e30f};
#pragma unroll
        for (int c = 0; c < 4; ++c)
            if (kq + (c << 4) >= NN) sc[c] = fneg;

        // ---- online softmax; write P-hi plane (swizzled) ----
#pragma unroll
        for (int r = 0; r < 4; ++r) {
            float rm = fmaxf(fmaxf(sc[0][r], sc[1][r]), fmaxf(sc[2][r], sc[3][r]));
            rm = fmaxf(rm, __shfl_xor(rm, 1));
            rm = fmaxf(rm, __shfl_xor(rm, 2));
            rm = fmaxf(rm, __shfl_xor(rm, 4));
            rm = fmaxf(rm, __shfl_xor(rm, 8));
            float mnew = fmaxf(m[r], rm);
            float corr = __expf(m[r] - mnew);
            m[r] = mnew;
            int prow  = ((lane >> 4) << 2) + r;
            int rowsw = (prow & 7) << 4;
            float rs = 0.f;
#pragma unroll
            for (int c = 0; c < 4; ++c) {
                float p = __expf(sc[c][r] - mnew);
                rs += p;
                int colb = ((c << 4) + (lane & 15)) << 1;
                *(us*)(smem + PB + prow * 128 + (colb ^ rowsw)) = f2bf(p);
            }
            rs += __shfl_xor(rs, 1);
            rs += __shfl_xor(rs, 2);
            rs += __shfl_xor(rs, 4);
            rs += __shfl_xor(rs, 8);
            lsum[r] = lsum[r] * corr + rs;
#pragma unroll
            for (int db = 0; db < 4; ++db) oa[db][r] *= corr;
        }

        // ---- O += P·V (single product) ----
        __builtin_amdgcn_s_setprio(1);
#pragma unroll
        for (int ks = 0; ks < 2; ++ks) {
            int prow = lane & 15;
            int poff = PB + prow * 128 + (((ks << 6) + ((lane >> 4) << 4)) ^ ((prow & 7) << 4));
            short8 pah = *(const short8*)(smem + poff);
#pragma unroll
            for (int db = 0; db < 4; ++db) {
                int vrow = (db << 4) + (lane & 15);
                int voff = vrow * 128 + (((ks << 6) + ((lane >> 4) << 4)) ^ ((vrow & 7) << 4));
                short8 vfh = *(const short8*)(smem + 16384 + voff);
                oa[db] = __builtin_amdgcn_mfma_f32_16x16x32_bf16(pah, vfh, oa[db], 0, 0, 0);
            }
        }
        __builtin_amdgcn_s_setprio(0);
        __syncthreads();
    }

    const int b = bh / NHEADS, h = bh - b * NHEADS;
#pragma unroll
    for (int r = 0; r < 4; ++r) {
        int q = q0 + (wv << 4) + ((lane >> 4) << 2) + r;
        if (q < NN) {
            float inv = 1.0f / lsum[r];
#pragma unroll
            for (int db = 0; db < 4; ++db) {
                int d = (db << 4) + (lane & 15);
                float v = oa[db][r] * inv;
                size_t idx = ((size_t)b * NN + q) * CC + h * HD + d;
                us hb = f2bf(v);
                Ohi[idx] = hb;
                Olo[idx] = f2bf(v - bf2f(hb));
            }
        }
    }
}

extern "C" void kernel_launch(void* const* d_in, const int* in_sizes, int n_in,
                              void* d_out, int out_size, void* d_ws, size_t ws_size,
                              hipStream_t stream) {
    const float* x      = (const float*)d_in[0];
    const float* qkv_w  = (const float*)d_in[1];
    const float* proj_w = (const float*)d_in[2];
    const float* proj_b = (const float*)d_in[3];
    const float* qnw    = (const float*)d_in[4];
    const float* knw    = (const float*)d_in[5];

    us* p = (us*)d_ws;
    us* Qhi = p;                 p += QSZ;
    us* Qlo = p;                 p += QSZ;
    us* Khi = p;                 p += QSZ;
    us* Klo = p;                 p += QSZ;
    us* Vth = p;                 p += VTSZ;
    us* Xhi = p;                 p += XSZ;   // reused as Ohi after qkv GEMM
    us* Xlo = p;                 p += XSZ;   // reused as Olo
    us* Wthi = p;                p += WTSZ;
    us* Wtlo = p;                p += WTSZ;
    us* Pwhi = p;                p += PWSZ;
    us* Pwlo = p;                p += PWSZ;

    split_x<<<dim3((int)(XSZ / 8 / 256)), 256, 0, stream>>>(x, Xhi, Xlo);
    tsplit<<<dim3(3 * CC / 64, CC / 64), 256, 0, stream>>>(qkv_w, Wthi, Wtlo, CC, 3 * CC);
    tsplit<<<dim3(CC / 64, CC / 64), 256, 0, stream>>>(proj_w, Pwhi, Pwlo, CC, CC);

    gemm_mfma<0><<<dim3(3 * CC / 128, (MM + 127) / 128), 256, 0, stream>>>(
        Wthi, Wtlo, Xhi, Xlo, Qhi, Qlo, Khi, Klo, Vth, nullptr, nullptr);
    norm_rope<<<dim3(BB * NHEADS * NN / 4, 2), 256, 0, stream>>>(Qhi, Qlo, Khi, Klo, qnw, knw);
    attn_mfma<<<dim3(8 * 408), 256, 0, stream>>>(Qhi, Qlo, Khi, Klo, Vth, Xhi, Xlo);
    gemm_mfma<1><<<dim3(CC / 128, (MM + 127) / 128), 256, 0, stream>>>(
        Pwhi, Pwlo, Xhi, Xlo, nullptr, nullptr, nullptr, nullptr, nullptr,
        (float*)d_out, proj_b);
}